// Round 4
// baseline (637.575 us; speedup 1.0000x reference)
//
#include <hip/hip_runtime.h>
#include <hip/hip_bf16.h>
#include <math.h>

#define KN 20
#define DD 64
#define WPB 4
#define NUSERS 100000
#define NITEMS 50000
#define NBU 1024   // blocks assigned to user table
#define NBI 512    // blocks assigned to item table

typedef __hip_bfloat16 bf16;

// ================= precompute Y = emb_table @ W1part (folded layer 1) ==========
__global__ __launch_bounds__(256, 4) void precompute_Y(
    const float* __restrict__ emb_u, const float* __restrict__ emb_i,
    const float* __restrict__ w1,
    bf16* __restrict__ Yu, bf16* __restrict__ Yi)
{
    __shared__ float stage[WPB][256];
    const int w    = threadIdx.x >> 6;
    const int lane = threadIdx.x & 63;

    const bool isU = (int)blockIdx.x < NBU;
    const float* __restrict__ emb  = isU ? emb_u : emb_i;
    bf16* __restrict__       Y     = isU ? Yu : Yi;
    const float* __restrict__ wsrc = isU ? w1 : (w1 + 64 * DD);
    const int ngroups = (isU ? NUSERS : NITEMS) / 4;
    const int bidx    = isU ? (int)blockIdx.x : ((int)blockIdx.x - NBU);
    const int nwaves  = (isU ? NBU : NBI) * WPB;
    const int wid     = bidx * WPB + w;

    float wreg[64];
    #pragma unroll
    for (int c = 0; c < 64; ++c) wreg[c] = wsrc[c * DD + lane];

    for (int g = wid; g < ngroups; g += nwaves) {
        float4 v = *(const float4*)&emb[(size_t)g * 256 + lane * 4];
        *(float4*)&stage[w][lane * 4] = v;
        #pragma unroll
        for (int r = 0; r < 4; ++r) {
            float a0 = 0.f, a1 = 0.f, a2 = 0.f, a3 = 0.f;
            #pragma unroll
            for (int q = 0; q < 16; ++q) {
                float4 e4 = *(const float4*)&stage[w][r * 64 + q * 4];
                a0 = fmaf(e4.x, wreg[q * 4 + 0], a0);
                a1 = fmaf(e4.y, wreg[q * 4 + 1], a1);
                a2 = fmaf(e4.z, wreg[q * 4 + 2], a2);
                a3 = fmaf(e4.w, wreg[q * 4 + 3], a3);
            }
            Y[(size_t)(g * 4 + r) * DD + lane] = (bf16)((a0 + a1) + (a2 + a3));
        }
    }
}

// ================= main fused kernel ==========================================
// All per-b metadata (uid/iid, neighbor indices, score rows) is wave-uniform ->
// forced onto the scalar pipe (s_load) via readfirstlane. Scores feed v_fmac as
// SGPR operands. No sbuf staging, no barriers (h1buf slot is wave-private).
__global__ __launch_bounds__(256, 8) void cnn_main(
    const int* __restrict__ user_idxs, const int* __restrict__ item_idxs,
    const int* __restrict__ user_idx_tensor, const float* __restrict__ user_scr_tensor,
    const int* __restrict__ item_idx_tensor, const float* __restrict__ item_scr_tensor,
    const bf16* __restrict__ Yu, const bf16* __restrict__ Yi,
    const float* __restrict__ b1,
    const float* __restrict__ w2, const float* __restrict__ b2,
    const float* __restrict__ w3, const float* __restrict__ b3,
    float* __restrict__ out, int Bn)
{
    __shared__ float h1buf[WPB][KN][DD];   // 20 KB -> 8 blocks/CU

    const int w    = threadIdx.x >> 6;
    const int lane = threadIdx.x & 63;
    int b0 = blockIdx.x * WPB + w;
    if (b0 >= Bn) b0 = Bn - 1;             // duplicate work, same value stored
    const int b = __builtin_amdgcn_readfirstlane(b0);   // assert wave-uniform

    const int uid = user_idxs[b];          // s_load
    const int iid = item_idxs[b];          // s_load

    int nvu[KN], nvi[KN];
    #pragma unroll
    for (int j = 0; j < KN; ++j) nvu[j] = user_idx_tensor[uid * KN + j];  // s_load x20
    #pragma unroll
    for (int j = 0; j < KN; ++j) nvi[j] = item_idx_tensor[iid * KN + j];  // s_load x20

    // ---- gather user Y rows (bf16, scalar base + lane offset) ----
    float y[KN];
    #pragma unroll
    for (int j = 0; j < KN; ++j)
        y[j] = (float)Yu[(size_t)nvu[j] * DD + lane];

    float h1acc[KN];
    const float b1v = b1[lane];
    #pragma unroll
    for (int k = 0; k < KN; ++k) h1acc[k] = b1v;

    // ---- user score matmul: scores via s_load, FMA with SGPR operand ----
    #pragma unroll 4
    for (int k = 0; k < KN; ++k) {
        const float* __restrict__ sr = user_scr_tensor + (size_t)nvu[k] * KN;
        float a = 0.f;
        #pragma unroll
        for (int j = 0; j < KN; ++j) a = fmaf(sr[j], y[j], a);
        h1acc[k] += a;
    }

    // ---- item side (reuse y regs) ----
    #pragma unroll
    for (int j = 0; j < KN; ++j)
        y[j] = (float)Yi[(size_t)nvi[j] * DD + lane];

    #pragma unroll 4
    for (int k = 0; k < KN; ++k) {
        const float* __restrict__ sr = item_scr_tensor + (size_t)nvi[k] * KN;
        float a = 0.f;
        #pragma unroll
        for (int j = 0; j < KN; ++j) a = fmaf(sr[j], y[j], a);
        h1acc[k] += a;
    }

    // ---- relu -> h1 to wave-private LDS slot (no barrier needed) ----
    #pragma unroll
    for (int k = 0; k < KN; ++k)
        h1buf[w][k][lane] = fmaxf(h1acc[k], 0.f);

    // ---- layer2 (half-wave c-split) + layer3 + sigmoid + mean, in-reg ----
    const int h = lane >> 5, o = lane & 31;
    float wreg2[32];
    #pragma unroll
    for (int cc = 0; cc < 32; ++cc)
        wreg2[cc] = w2[(h * 32 + cc) * 32 + o];
    const float b2v = b2[o];
    const float w3v = w3[o];
    const float b3v = b3[0];

    float sum = 0.f;
    #pragma unroll
    for (int k = 0; k < KN; ++k) {
        const float4* hp = (const float4*)&h1buf[w][k][h * 32];
        float a = 0.f;
        #pragma unroll
        for (int q = 0; q < 8; ++q) {
            float4 v = hp[q];
            a = fmaf(v.x, wreg2[4*q+0], a);
            a = fmaf(v.y, wreg2[4*q+1], a);
            a = fmaf(v.z, wreg2[4*q+2], a);
            a = fmaf(v.w, wreg2[4*q+3], a);
        }
        float h2 = a + __shfl_xor(a, 32) + b2v;   // combine the two c-halves
        h2 = fmaxf(h2, 0.f);
        float p = h2 * w3v;
        #pragma unroll
        for (int off = 16; off > 0; off >>= 1)
            p += __shfl_xor(p, off);              // reduce over 32 out-cols
        float logit = p + b3v;
        float e = __expf(-logit);
        sum += __builtin_amdgcn_rcpf(1.f + e);
    }
    if (lane == 0) out[b] = sum * (1.f / KN);
}

extern "C" void kernel_launch(void* const* d_in, const int* in_sizes, int n_in,
                              void* d_out, int out_size, void* d_ws, size_t ws_size,
                              hipStream_t stream) {
    const int*   user_idxs       = (const int*)  d_in[0];
    const int*   item_idxs       = (const int*)  d_in[1];
    const int*   user_idx_tensor = (const int*)  d_in[2];
    const float* user_scr_tensor = (const float*)d_in[3];
    const int*   item_idx_tensor = (const int*)  d_in[4];
    const float* item_scr_tensor = (const float*)d_in[5];
    const float* user_emb        = (const float*)d_in[6];
    const float* item_emb        = (const float*)d_in[7];
    const float* w1 = (const float*)d_in[8];
    const float* b1 = (const float*)d_in[9];
    const float* w2 = (const float*)d_in[10];
    const float* b2 = (const float*)d_in[11];
    const float* w3 = (const float*)d_in[12];
    const float* b3 = (const float*)d_in[13];
    float* out = (float*)d_out;

    const int Bn = in_sizes[0];

    // workspace layout: Yu bf16 [100000][64] then Yi bf16 [50000][64]
    bf16* Yu = (bf16*)d_ws;
    bf16* Yi = Yu + (size_t)NUSERS * DD;

    precompute_Y<<<NBU + NBI, 256, 0, stream>>>(user_emb, item_emb, w1, Yu, Yi);

    const int grid = (Bn + WPB - 1) / WPB;
    cnn_main<<<grid, 256, 0, stream>>>(
        user_idxs, item_idxs, user_idx_tensor, user_scr_tensor,
        item_idx_tensor, item_scr_tensor, Yu, Yi,
        b1, w2, b2, w3, b3, out, Bn);
}

// Round 5
// 500.503 us; speedup vs baseline: 1.2739x; 1.2739x over previous
//
#include <hip/hip_runtime.h>
#include <hip/hip_bf16.h>
#include <math.h>

#define KN 20
#define DD 64
#define WPB 4
#define NUSERS 100000
#define NITEMS 50000
#define NBU 1024   // blocks assigned to user table
#define NBI 512    // blocks assigned to item table

typedef __hip_bfloat16 bf16;

// ================= precompute Y = emb_table @ W1part (folded layer 1) ==========
__global__ __launch_bounds__(256, 4) void precompute_Y(
    const float* __restrict__ emb_u, const float* __restrict__ emb_i,
    const float* __restrict__ w1,
    bf16* __restrict__ Yu, bf16* __restrict__ Yi)
{
    __shared__ float stage[WPB][256];
    const int w    = threadIdx.x >> 6;
    const int lane = threadIdx.x & 63;

    const bool isU = (int)blockIdx.x < NBU;
    const float* __restrict__ emb  = isU ? emb_u : emb_i;
    bf16* __restrict__       Y     = isU ? Yu : Yi;
    const float* __restrict__ wsrc = isU ? w1 : (w1 + 64 * DD);
    const int ngroups = (isU ? NUSERS : NITEMS) / 4;
    const int bidx    = isU ? (int)blockIdx.x : ((int)blockIdx.x - NBU);
    const int nwaves  = (isU ? NBU : NBI) * WPB;
    const int wid     = bidx * WPB + w;

    float wreg[64];
    #pragma unroll
    for (int c = 0; c < 64; ++c) wreg[c] = wsrc[c * DD + lane];

    for (int g = wid; g < ngroups; g += nwaves) {
        float4 v = *(const float4*)&emb[(size_t)g * 256 + lane * 4];
        *(float4*)&stage[w][lane * 4] = v;
        #pragma unroll
        for (int r = 0; r < 4; ++r) {
            float a0 = 0.f, a1 = 0.f, a2 = 0.f, a3 = 0.f;
            #pragma unroll
            for (int q = 0; q < 16; ++q) {
                float4 e4 = *(const float4*)&stage[w][r * 64 + q * 4];
                a0 = fmaf(e4.x, wreg[q * 4 + 0], a0);
                a1 = fmaf(e4.y, wreg[q * 4 + 1], a1);
                a2 = fmaf(e4.z, wreg[q * 4 + 2], a2);
                a3 = fmaf(e4.w, wreg[q * 4 + 3], a3);
            }
            Y[(size_t)(g * 4 + r) * DD + lane] = (bf16)((a0 + a1) + (a2 + a3));
        }
    }
}

// ================= main fused kernel ==========================================
// Wave-uniform metadata (uid/iid, neighbor indices, score rows) on the scalar
// pipe (s_load). Scores feed v_fmac as the (single) SGPR operand. No sbuf, no
// barriers. launch_bounds(256,4): 128-VGPR cap -- R4's (256,8) forced scratch
// spills (WRITE_SIZE 906 MB, 650 us); demand is ~70 VGPR, so cap must stay >=128.
__global__ __launch_bounds__(256, 4) void cnn_main(
    const int* __restrict__ user_idxs, const int* __restrict__ item_idxs,
    const int* __restrict__ user_idx_tensor, const float* __restrict__ user_scr_tensor,
    const int* __restrict__ item_idx_tensor, const float* __restrict__ item_scr_tensor,
    const bf16* __restrict__ Yu, const bf16* __restrict__ Yi,
    const float* __restrict__ b1,
    const float* __restrict__ w2, const float* __restrict__ b2,
    const float* __restrict__ w3, const float* __restrict__ b3,
    float* __restrict__ out, int Bn)
{
    __shared__ float h1buf[WPB][KN][DD];   // 20 KB/block

    const int w    = threadIdx.x >> 6;
    const int lane = threadIdx.x & 63;
    int b0 = blockIdx.x * WPB + w;
    if (b0 >= Bn) b0 = Bn - 1;             // duplicate work, same value stored
    const int b = __builtin_amdgcn_readfirstlane(b0);   // assert wave-uniform

    const int uid = user_idxs[b];          // s_load
    const int iid = item_idxs[b];          // s_load

    int nvu[KN], nvi[KN];
    #pragma unroll
    for (int j = 0; j < KN; ++j) nvu[j] = user_idx_tensor[uid * KN + j];  // s_load x20
    #pragma unroll
    for (int j = 0; j < KN; ++j) nvi[j] = item_idx_tensor[iid * KN + j];  // s_load x20

    // ---- gather user Y rows (bf16, scalar base + lane offset) ----
    float y[KN];
    #pragma unroll
    for (int j = 0; j < KN; ++j)
        y[j] = (float)Yu[(size_t)nvu[j] * DD + lane];

    float h1acc[KN];
    const float b1v = b1[lane];
    #pragma unroll
    for (int k = 0; k < KN; ++k) h1acc[k] = b1v;

    // ---- user score matmul: scores via s_load, FMA with SGPR operand ----
    #pragma unroll 4
    for (int k = 0; k < KN; ++k) {
        const float* __restrict__ sr = user_scr_tensor + (size_t)nvu[k] * KN;
        float a = 0.f;
        #pragma unroll
        for (int j = 0; j < KN; ++j) a = fmaf(sr[j], y[j], a);
        h1acc[k] += a;
    }

    // ---- item side (reuse y regs) ----
    #pragma unroll
    for (int j = 0; j < KN; ++j)
        y[j] = (float)Yi[(size_t)nvi[j] * DD + lane];

    #pragma unroll 4
    for (int k = 0; k < KN; ++k) {
        const float* __restrict__ sr = item_scr_tensor + (size_t)nvi[k] * KN;
        float a = 0.f;
        #pragma unroll
        for (int j = 0; j < KN; ++j) a = fmaf(sr[j], y[j], a);
        h1acc[k] += a;
    }

    // ---- relu -> h1 to wave-private LDS slot (no barrier needed) ----
    #pragma unroll
    for (int k = 0; k < KN; ++k)
        h1buf[w][k][lane] = fmaxf(h1acc[k], 0.f);

    // ---- layer2 (half-wave c-split) + layer3 + sigmoid + mean, in-reg ----
    const int h = lane >> 5, o = lane & 31;
    float wreg2[32];
    #pragma unroll
    for (int cc = 0; cc < 32; ++cc)
        wreg2[cc] = w2[(h * 32 + cc) * 32 + o];
    const float b2v = b2[o];
    const float w3v = w3[o];
    const float b3v = b3[0];

    float sum = 0.f;
    #pragma unroll
    for (int k = 0; k < KN; ++k) {
        const float4* hp = (const float4*)&h1buf[w][k][h * 32];
        float a = 0.f;
        #pragma unroll
        for (int q = 0; q < 8; ++q) {
            float4 v = hp[q];
            a = fmaf(v.x, wreg2[4*q+0], a);
            a = fmaf(v.y, wreg2[4*q+1], a);
            a = fmaf(v.z, wreg2[4*q+2], a);
            a = fmaf(v.w, wreg2[4*q+3], a);
        }
        float h2 = a + __shfl_xor(a, 32) + b2v;   // combine the two c-halves
        h2 = fmaxf(h2, 0.f);
        float p = h2 * w3v;
        #pragma unroll
        for (int off = 16; off > 0; off >>= 1)
            p += __shfl_xor(p, off);              // reduce over 32 out-cols
        float logit = p + b3v;
        sum += 1.f / (1.f + __expf(-logit));
    }
    if (lane == 0) out[b] = sum * (1.f / KN);
}

extern "C" void kernel_launch(void* const* d_in, const int* in_sizes, int n_in,
                              void* d_out, int out_size, void* d_ws, size_t ws_size,
                              hipStream_t stream) {
    const int*   user_idxs       = (const int*)  d_in[0];
    const int*   item_idxs       = (const int*)  d_in[1];
    const int*   user_idx_tensor = (const int*)  d_in[2];
    const float* user_scr_tensor = (const float*)d_in[3];
    const int*   item_idx_tensor = (const int*)  d_in[4];
    const float* item_scr_tensor = (const float*)d_in[5];
    const float* user_emb        = (const float*)d_in[6];
    const float* item_emb        = (const float*)d_in[7];
    const float* w1 = (const float*)d_in[8];
    const float* b1 = (const float*)d_in[9];
    const float* w2 = (const float*)d_in[10];
    const float* b2 = (const float*)d_in[11];
    const float* w3 = (const float*)d_in[12];
    const float* b3 = (const float*)d_in[13];
    float* out = (float*)d_out;

    const int Bn = in_sizes[0];

    // workspace layout: Yu bf16 [100000][64] then Yi bf16 [50000][64]
    bf16* Yu = (bf16*)d_ws;
    bf16* Yi = Yu + (size_t)NUSERS * DD;

    precompute_Y<<<NBU + NBI, 256, 0, stream>>>(user_emb, item_emb, w1, Yu, Yi);

    const int grid = (Bn + WPB - 1) / WPB;
    cnn_main<<<grid, 256, 0, stream>>>(
        user_idxs, item_idxs, user_idx_tensor, user_scr_tensor,
        item_idx_tensor, item_scr_tensor, Yu, Yi,
        b1, w2, b2, w3, b3, out, Bn);
}

// Round 6
// 121.675 us; speedup vs baseline: 5.2400x; 4.1135x over previous
//
#include <hip/hip_runtime.h>
#include <hip/hip_bf16.h>
#include <math.h>

#define KN 20
#define DD 64
#define WPB 4
#define NUSERS 100000
#define NITEMS 50000
#define NBU 1024   // blocks assigned to user table
#define NBI 512    // blocks assigned to item table

typedef __hip_bfloat16 bf16;

// ================= precompute Y = emb_table @ W1part (folded layer 1) ==========
__global__ __launch_bounds__(256, 4) void precompute_Y(
    const float* __restrict__ emb_u, const float* __restrict__ emb_i,
    const float* __restrict__ w1,
    bf16* __restrict__ Yu, bf16* __restrict__ Yi)
{
    __shared__ float stage[WPB][256];
    const int w    = threadIdx.x >> 6;
    const int lane = threadIdx.x & 63;

    const bool isU = (int)blockIdx.x < NBU;
    const float* __restrict__ emb  = isU ? emb_u : emb_i;
    bf16* __restrict__       Y     = isU ? Yu : Yi;
    const float* __restrict__ wsrc = isU ? w1 : (w1 + 64 * DD);
    const int ngroups = (isU ? NUSERS : NITEMS) / 4;
    const int bidx    = isU ? (int)blockIdx.x : ((int)blockIdx.x - NBU);
    const int nwaves  = (isU ? NBU : NBI) * WPB;
    const int wid     = bidx * WPB + w;

    float wreg[64];
    #pragma unroll
    for (int c = 0; c < 64; ++c) wreg[c] = wsrc[c * DD + lane];

    for (int g = wid; g < ngroups; g += nwaves) {
        float4 v = *(const float4*)&emb[(size_t)g * 256 + lane * 4];
        *(float4*)&stage[w][lane * 4] = v;
        #pragma unroll
        for (int r = 0; r < 4; ++r) {
            float a0 = 0.f, a1 = 0.f, a2 = 0.f, a3 = 0.f;
            #pragma unroll
            for (int q = 0; q < 16; ++q) {
                float4 e4 = *(const float4*)&stage[w][r * 64 + q * 4];
                a0 = fmaf(e4.x, wreg[q * 4 + 0], a0);
                a1 = fmaf(e4.y, wreg[q * 4 + 1], a1);
                a2 = fmaf(e4.z, wreg[q * 4 + 2], a2);
                a3 = fmaf(e4.w, wreg[q * 4 + 3], a3);
            }
            Y[(size_t)(g * 4 + r) * DD + lane] = (bf16)((a0 + a1) + (a2 + a3));
        }
    }
}

// ================= main fused kernel ==========================================
// R3 structure (proven: VGPR 52, no spills, 104 us) with occupancy fixes:
//  - single union LDS buffer: scores [0..799] die before h1 [0..1279] is born
//    (both wave-private) -> 20.5 KB/block -> 7 blocks/CU (was 4 at 33 KB)
//  - no __syncthreads anywhere: all LDS wave-private, compiler lgkmcnt orders
// DO NOT force scores to SGPRs (R4/R5: allocator spills arrays, 1 GB scratch).
__global__ __launch_bounds__(256, 4) void cnn_main(
    const int* __restrict__ user_idxs, const int* __restrict__ item_idxs,
    const int* __restrict__ user_idx_tensor, const float* __restrict__ user_scr_tensor,
    const int* __restrict__ item_idx_tensor, const float* __restrict__ item_scr_tensor,
    const bf16* __restrict__ Yu, const bf16* __restrict__ Yi,
    const float* __restrict__ b1,
    const float* __restrict__ w2, const float* __restrict__ b2,
    const float* __restrict__ w3, const float* __restrict__ b3,
    float* __restrict__ out, int Bn)
{
    __shared__ float buf[WPB][KN * DD];    // [0..799] scores, then [0..1279] h1

    const int w    = threadIdx.x >> 6;
    const int lane = threadIdx.x & 63;
    const int b = blockIdx.x * WPB + w;
    if (b >= Bn) return;                   // no barriers -> divergence-safe

    const int uid = user_idxs[b];
    const int iid = item_idxs[b];

    int nvu = 0, nvi = 0;
    if (lane < KN) {
        nvu = user_idx_tensor[uid * KN + lane];
        nvi = item_idx_tensor[iid * KN + lane];
    }

    // ---- stage both 20x20 score blocks into wave-private LDS ----
    for (int e = lane; e < 2 * KN * KN; e += 64) {
        int eu   = (e >= KN * KN) ? (e - KN * KN) : e;
        int r    = eu / KN;
        int c    = eu - r * KN;
        int rowu = __shfl(nvu, r);
        int rowi = __shfl(nvi, r);
        float s  = (e >= KN * KN) ? item_scr_tensor[rowi * KN + c]
                                  : user_scr_tensor[rowu * KN + c];
        buf[w][e] = s;
    }

    // ---- gather user Y rows (bf16, coalesced 128B/row) ----
    float y[KN];
    #pragma unroll
    for (int j = 0; j < KN; ++j) {
        int row = __shfl(nvu, j);
        y[j] = (float)Yu[(long)row * DD + lane];
    }

    float h1acc[KN];
    const float b1v = b1[lane];
    #pragma unroll
    for (int k = 0; k < KN; ++k) h1acc[k] = b1v;

    // ---- user score matmul: h1acc[k] += sum_j s[k][j] * yu[j][lane] ----
    #pragma unroll
    for (int k = 0; k < KN; ++k) {
        const float4* sp = (const float4*)&buf[w][k * KN];
        float s[KN];
        #pragma unroll
        for (int q = 0; q < KN / 4; ++q) {
            float4 v = sp[q];
            s[4*q] = v.x; s[4*q+1] = v.y; s[4*q+2] = v.z; s[4*q+3] = v.w;
        }
        float a = 0.f;
        #pragma unroll
        for (int j = 0; j < KN; ++j) a = fmaf(s[j], y[j], a);
        h1acc[k] += a;
    }

    // ---- item side (reuse y regs) ----
    #pragma unroll
    for (int j = 0; j < KN; ++j) {
        int row = __shfl(nvi, j);
        y[j] = (float)Yi[(long)row * DD + lane];
    }
    #pragma unroll
    for (int k = 0; k < KN; ++k) {
        const float4* sp = (const float4*)&buf[w][KN * KN + k * KN];
        float s[KN];
        #pragma unroll
        for (int q = 0; q < KN / 4; ++q) {
            float4 v = sp[q];
            s[4*q] = v.x; s[4*q+1] = v.y; s[4*q+2] = v.z; s[4*q+3] = v.w;
        }
        float a = 0.f;
        #pragma unroll
        for (int j = 0; j < KN; ++j) a = fmaf(s[j], y[j], a);
        h1acc[k] += a;
    }

    // ---- relu -> h1 into the SAME wave-private buffer (scores now dead) ----
    #pragma unroll
    for (int k = 0; k < KN; ++k)
        buf[w][k * DD + lane] = fmaxf(h1acc[k], 0.f);

    // ---- layer2 (half-wave c-split) + layer3 + sigmoid + mean, in-reg ----
    const int h = lane >> 5, o = lane & 31;
    float wreg2[32];
    #pragma unroll
    for (int cc = 0; cc < 32; ++cc)
        wreg2[cc] = w2[(h * 32 + cc) * 32 + o];
    const float b2v = b2[o];
    const float w3v = w3[o];
    const float b3v = b3[0];

    float sum = 0.f;
    #pragma unroll
    for (int k = 0; k < KN; ++k) {
        const float4* hp = (const float4*)&buf[w][k * DD + h * 32];
        float a = 0.f;
        #pragma unroll
        for (int q = 0; q < 8; ++q) {
            float4 v = hp[q];
            a = fmaf(v.x, wreg2[4*q+0], a);
            a = fmaf(v.y, wreg2[4*q+1], a);
            a = fmaf(v.z, wreg2[4*q+2], a);
            a = fmaf(v.w, wreg2[4*q+3], a);
        }
        float h2 = a + __shfl_xor(a, 32) + b2v;   // combine the two c-halves
        h2 = fmaxf(h2, 0.f);
        float p = h2 * w3v;
        #pragma unroll
        for (int off = 16; off > 0; off >>= 1)
            p += __shfl_xor(p, off);              // reduce over 32 out-cols
        float logit = p + b3v;
        sum += 1.f / (1.f + __expf(-logit));
    }
    if (lane == 0) out[b] = sum * (1.f / KN);
}

extern "C" void kernel_launch(void* const* d_in, const int* in_sizes, int n_in,
                              void* d_out, int out_size, void* d_ws, size_t ws_size,
                              hipStream_t stream) {
    const int*   user_idxs       = (const int*)  d_in[0];
    const int*   item_idxs       = (const int*)  d_in[1];
    const int*   user_idx_tensor = (const int*)  d_in[2];
    const float* user_scr_tensor = (const float*)d_in[3];
    const int*   item_idx_tensor = (const int*)  d_in[4];
    const float* item_scr_tensor = (const float*)d_in[5];
    const float* user_emb        = (const float*)d_in[6];
    const float* item_emb        = (const float*)d_in[7];
    const float* w1 = (const float*)d_in[8];
    const float* b1 = (const float*)d_in[9];
    const float* w2 = (const float*)d_in[10];
    const float* b2 = (const float*)d_in[11];
    const float* w3 = (const float*)d_in[12];
    const float* b3 = (const float*)d_in[13];
    float* out = (float*)d_out;

    const int Bn = in_sizes[0];

    // workspace layout: Yu bf16 [100000][64] then Yi bf16 [50000][64]
    bf16* Yu = (bf16*)d_ws;
    bf16* Yi = Yu + (size_t)NUSERS * DD;

    precompute_Y<<<NBU + NBI, 256, 0, stream>>>(user_emb, item_emb, w1, Yu, Yi);

    const int grid = (Bn + WPB - 1) / WPB;
    cnn_main<<<grid, 256, 0, stream>>>(
        user_idxs, item_idxs, user_idx_tensor, user_scr_tensor,
        item_idx_tensor, item_scr_tensor, Yu, Yi,
        b1, w2, b2, w3, b3, out, Bn);
}

// Round 7
// 119.091 us; speedup vs baseline: 5.3537x; 1.0217x over previous
//
#include <hip/hip_runtime.h>
#include <hip/hip_bf16.h>
#include <math.h>

#define KN 20
#define DD 64
#define WPB 4
#define NUSERS 100000
#define NITEMS 50000
#define NBU 1024   // blocks assigned to user table
#define NBI 512    // blocks assigned to item table

typedef __hip_bfloat16 bf16;

// ================= precompute Y = emb_table @ W1part (folded layer 1) ==========
__global__ __launch_bounds__(256, 4) void precompute_Y(
    const float* __restrict__ emb_u, const float* __restrict__ emb_i,
    const float* __restrict__ w1,
    bf16* __restrict__ Yu, bf16* __restrict__ Yi)
{
    __shared__ float stage[WPB][256];
    const int w    = threadIdx.x >> 6;
    const int lane = threadIdx.x & 63;

    const bool isU = (int)blockIdx.x < NBU;
    const float* __restrict__ emb  = isU ? emb_u : emb_i;
    bf16* __restrict__       Y     = isU ? Yu : Yi;
    const float* __restrict__ wsrc = isU ? w1 : (w1 + 64 * DD);
    const int ngroups = (isU ? NUSERS : NITEMS) / 4;
    const int bidx    = isU ? (int)blockIdx.x : ((int)blockIdx.x - NBU);
    const int nwaves  = (isU ? NBU : NBI) * WPB;
    const int wid     = bidx * WPB + w;

    float wreg[64];
    #pragma unroll
    for (int c = 0; c < 64; ++c) wreg[c] = wsrc[c * DD + lane];

    for (int g = wid; g < ngroups; g += nwaves) {
        float4 v = *(const float4*)&emb[(size_t)g * 256 + lane * 4];
        *(float4*)&stage[w][lane * 4] = v;
        #pragma unroll
        for (int r = 0; r < 4; ++r) {
            float a0 = 0.f, a1 = 0.f, a2 = 0.f, a3 = 0.f;
            #pragma unroll
            for (int q = 0; q < 16; ++q) {
                float4 e4 = *(const float4*)&stage[w][r * 64 + q * 4];
                a0 = fmaf(e4.x, wreg[q * 4 + 0], a0);
                a1 = fmaf(e4.y, wreg[q * 4 + 1], a1);
                a2 = fmaf(e4.z, wreg[q * 4 + 2], a2);
                a3 = fmaf(e4.w, wreg[q * 4 + 3], a3);
            }
            Y[(size_t)(g * 4 + r) * DD + lane] = (bf16)((a0 + a1) + (a2 + a3));
        }
    }
}

// ================= main fused kernel ==========================================
// R6 structure (union LDS buffer, barrier-free, VGPR 56, no spills) with
// launch_bounds(256,8): R3/R5/R6 all pinned at ~40% occupancy under (256,4)
// while R4's (256,8) showed 57% -- the 2nd arg is governing resident waves/EU.
// VGPR demand 56 fits the 64-cap, so no spill risk this time (R4's demand ~100).
__global__ __launch_bounds__(256, 8) void cnn_main(
    const int* __restrict__ user_idxs, const int* __restrict__ item_idxs,
    const int* __restrict__ user_idx_tensor, const float* __restrict__ user_scr_tensor,
    const int* __restrict__ item_idx_tensor, const float* __restrict__ item_scr_tensor,
    const bf16* __restrict__ Yu, const bf16* __restrict__ Yi,
    const float* __restrict__ b1,
    const float* __restrict__ w2, const float* __restrict__ b2,
    const float* __restrict__ w3, const float* __restrict__ b3,
    float* __restrict__ out, int Bn)
{
    __shared__ float buf[WPB][KN * DD];    // [0..799] scores, then [0..1279] h1

    const int w    = threadIdx.x >> 6;
    const int lane = threadIdx.x & 63;
    const int b = blockIdx.x * WPB + w;
    if (b >= Bn) return;                   // no barriers -> divergence-safe

    const int uid = user_idxs[b];
    const int iid = item_idxs[b];

    int nvu = 0, nvi = 0;
    if (lane < KN) {
        nvu = user_idx_tensor[uid * KN + lane];
        nvi = item_idx_tensor[iid * KN + lane];
    }

    // ---- stage both 20x20 score blocks into wave-private LDS ----
    for (int e = lane; e < 2 * KN * KN; e += 64) {
        int eu   = (e >= KN * KN) ? (e - KN * KN) : e;
        int r    = eu / KN;
        int c    = eu - r * KN;
        int rowu = __shfl(nvu, r);
        int rowi = __shfl(nvi, r);
        float s  = (e >= KN * KN) ? item_scr_tensor[rowi * KN + c]
                                  : user_scr_tensor[rowu * KN + c];
        buf[w][e] = s;
    }

    // ---- gather user Y rows (bf16, coalesced 128B/row) ----
    float y[KN];
    #pragma unroll
    for (int j = 0; j < KN; ++j) {
        int row = __shfl(nvu, j);
        y[j] = (float)Yu[(long)row * DD + lane];
    }

    float h1acc[KN];
    const float b1v = b1[lane];
    #pragma unroll
    for (int k = 0; k < KN; ++k) h1acc[k] = b1v;

    // ---- user score matmul: h1acc[k] += sum_j s[k][j] * yu[j][lane] ----
    #pragma unroll
    for (int k = 0; k < KN; ++k) {
        const float4* sp = (const float4*)&buf[w][k * KN];
        float s[KN];
        #pragma unroll
        for (int q = 0; q < KN / 4; ++q) {
            float4 v = sp[q];
            s[4*q] = v.x; s[4*q+1] = v.y; s[4*q+2] = v.z; s[4*q+3] = v.w;
        }
        float a = 0.f;
        #pragma unroll
        for (int j = 0; j < KN; ++j) a = fmaf(s[j], y[j], a);
        h1acc[k] += a;
    }

    // ---- item side (reuse y regs) ----
    #pragma unroll
    for (int j = 0; j < KN; ++j) {
        int row = __shfl(nvi, j);
        y[j] = (float)Yi[(long)row * DD + lane];
    }
    #pragma unroll
    for (int k = 0; k < KN; ++k) {
        const float4* sp = (const float4*)&buf[w][KN * KN + k * KN];
        float s[KN];
        #pragma unroll
        for (int q = 0; q < KN / 4; ++q) {
            float4 v = sp[q];
            s[4*q] = v.x; s[4*q+1] = v.y; s[4*q+2] = v.z; s[4*q+3] = v.w;
        }
        float a = 0.f;
        #pragma unroll
        for (int j = 0; j < KN; ++j) a = fmaf(s[j], y[j], a);
        h1acc[k] += a;
    }

    // ---- relu -> h1 into the SAME wave-private buffer (scores now dead) ----
    #pragma unroll
    for (int k = 0; k < KN; ++k)
        buf[w][k * DD + lane] = fmaxf(h1acc[k], 0.f);

    // ---- layer2 (half-wave c-split) + layer3 + sigmoid + mean, in-reg ----
    const int h = lane >> 5, o = lane & 31;
    float wreg2[32];
    #pragma unroll
    for (int cc = 0; cc < 32; ++cc)
        wreg2[cc] = w2[(h * 32 + cc) * 32 + o];
    const float b2v = b2[o];
    const float w3v = w3[o];
    const float b3v = b3[0];

    float sum = 0.f;
    #pragma unroll
    for (int k = 0; k < KN; ++k) {
        const float4* hp = (const float4*)&buf[w][k * DD + h * 32];
        float a = 0.f;
        #pragma unroll
        for (int q = 0; q < 8; ++q) {
            float4 v = hp[q];
            a = fmaf(v.x, wreg2[4*q+0], a);
            a = fmaf(v.y, wreg2[4*q+1], a);
            a = fmaf(v.z, wreg2[4*q+2], a);
            a = fmaf(v.w, wreg2[4*q+3], a);
        }
        float h2 = a + __shfl_xor(a, 32) + b2v;   // combine the two c-halves
        h2 = fmaxf(h2, 0.f);
        float p = h2 * w3v;
        #pragma unroll
        for (int off = 16; off > 0; off >>= 1)
            p += __shfl_xor(p, off);              // reduce over 32 out-cols
        float logit = p + b3v;
        sum += 1.f / (1.f + __expf(-logit));
    }
    if (lane == 0) out[b] = sum * (1.f / KN);
}

extern "C" void kernel_launch(void* const* d_in, const int* in_sizes, int n_in,
                              void* d_out, int out_size, void* d_ws, size_t ws_size,
                              hipStream_t stream) {
    const int*   user_idxs       = (const int*)  d_in[0];
    const int*   item_idxs       = (const int*)  d_in[1];
    const int*   user_idx_tensor = (const int*)  d_in[2];
    const float* user_scr_tensor = (const float*)d_in[3];
    const int*   item_idx_tensor = (const int*)  d_in[4];
    const float* item_scr_tensor = (const float*)d_in[5];
    const float* user_emb        = (const float*)d_in[6];
    const float* item_emb        = (const float*)d_in[7];
    const float* w1 = (const float*)d_in[8];
    const float* b1 = (const float*)d_in[9];
    const float* w2 = (const float*)d_in[10];
    const float* b2 = (const float*)d_in[11];
    const float* w3 = (const float*)d_in[12];
    const float* b3 = (const float*)d_in[13];
    float* out = (float*)d_out;

    const int Bn = in_sizes[0];

    // workspace layout: Yu bf16 [100000][64] then Yi bf16 [50000][64]
    bf16* Yu = (bf16*)d_ws;
    bf16* Yi = Yu + (size_t)NUSERS * DD;

    precompute_Y<<<NBU + NBI, 256, 0, stream>>>(user_emb, item_emb, w1, Yu, Yi);

    const int grid = (Bn + WPB - 1) / WPB;
    cnn_main<<<grid, 256, 0, stream>>>(
        user_idxs, item_idxs, user_idx_tensor, user_scr_tensor,
        item_idx_tensor, item_scr_tensor, Yu, Yi,
        b1, w2, b2, w3, b3, out, Bn);
}

// Round 8
// 90.201 us; speedup vs baseline: 7.0684x; 1.3203x over previous
//
#include <hip/hip_runtime.h>
#include <hip/hip_bf16.h>
#include <math.h>

#define KN 20
#define DD 64
#define WPB 4
#define NUSERS 100000
#define NITEMS 50000
#define NBU 1024   // blocks assigned to user table
#define NBI 512    // blocks assigned to item table

typedef __hip_bfloat16 bf16;
typedef __attribute__((ext_vector_type(8))) short short8;   // 8 bf16 (4 VGPRs)
typedef __attribute__((ext_vector_type(16))) float f32x16;  // MFMA 32x32 acc

__device__ inline ushort f2bf(float f) {                    // fp32 -> bf16 RNE
    unsigned u = __builtin_bit_cast(unsigned, f);
    u += 0x7fffu + ((u >> 16) & 1u);
    return (ushort)(u >> 16);
}

// ================= precompute Y = emb_table @ W1part (folded layer 1) ==========
__global__ __launch_bounds__(256, 4) void precompute_Y(
    const float* __restrict__ emb_u, const float* __restrict__ emb_i,
    const float* __restrict__ w1,
    bf16* __restrict__ Yu, bf16* __restrict__ Yi)
{
    __shared__ float stage[WPB][256];
    const int w    = threadIdx.x >> 6;
    const int lane = threadIdx.x & 63;

    const bool isU = (int)blockIdx.x < NBU;
    const float* __restrict__ emb  = isU ? emb_u : emb_i;
    bf16* __restrict__       Y     = isU ? Yu : Yi;
    const float* __restrict__ wsrc = isU ? w1 : (w1 + 64 * DD);
    const int ngroups = (isU ? NUSERS : NITEMS) / 4;
    const int bidx    = isU ? (int)blockIdx.x : ((int)blockIdx.x - NBU);
    const int nwaves  = (isU ? NBU : NBI) * WPB;
    const int wid     = bidx * WPB + w;

    float wreg[64];
    #pragma unroll
    for (int c = 0; c < 64; ++c) wreg[c] = wsrc[c * DD + lane];

    for (int g = wid; g < ngroups; g += nwaves) {
        float4 v = *(const float4*)&emb[(size_t)g * 256 + lane * 4];
        *(float4*)&stage[w][lane * 4] = v;
        #pragma unroll
        for (int r = 0; r < 4; ++r) {
            float a0 = 0.f, a1 = 0.f, a2 = 0.f, a3 = 0.f;
            #pragma unroll
            for (int q = 0; q < 16; ++q) {
                float4 e4 = *(const float4*)&stage[w][r * 64 + q * 4];
                a0 = fmaf(e4.x, wreg[q * 4 + 0], a0);
                a1 = fmaf(e4.y, wreg[q * 4 + 1], a1);
                a2 = fmaf(e4.z, wreg[q * 4 + 2], a2);
                a3 = fmaf(e4.w, wreg[q * 4 + 3], a3);
            }
            Y[(size_t)(g * 4 + r) * DD + lane] = (bf16)((a0 + a1) + (a2 + a3));
        }
    }
}

// ================= main fused kernel ==========================================
// h1 stage on the MATRIX pipe: h1(20x64) = Su(20x20)@Yu_g + Si(20x20)@Yi_g via
// v_mfma_f32_32x32x16_bf16, 2 N-tiles x 2 K-steps x 2 sides = 8 MFMA into one C.
// A = score rows direct from global (fp32->bf16); B = Y cols direct from global
// (already bf16). Only B rows k>=20 need zeroing (then A k>=20 cols and C rows
// >=20 are don't-care). C layout (m74/m101): col=lane&31,
// row=(reg&3)+8*(reg>>2)+4*(lane>>5). Layer2/3 unchanged from R7.
// R4/R5 lesson: keep (256,4) -- tighter caps spill per-thread arrays to scratch.
__global__ __launch_bounds__(256, 4) void cnn_main(
    const int* __restrict__ user_idxs, const int* __restrict__ item_idxs,
    const int* __restrict__ user_idx_tensor, const float* __restrict__ user_scr_tensor,
    const int* __restrict__ item_idx_tensor, const float* __restrict__ item_scr_tensor,
    const bf16* __restrict__ Yu, const bf16* __restrict__ Yi,
    const float* __restrict__ b1,
    const float* __restrict__ w2, const float* __restrict__ b2,
    const float* __restrict__ w3, const float* __restrict__ b3,
    float* __restrict__ out, int Bn)
{
    __shared__ float buf[WPB][KN * DD];    // h1 rows 0..19 (20.5 KB/block)

    const int w    = threadIdx.x >> 6;
    const int lane = threadIdx.x & 63;
    const int g    = lane >> 5;            // half-wave group (k-octet select)
    const int c    = lane & 31;            // tile column
    const int b = blockIdx.x * WPB + w;
    if (b >= Bn) return;                   // no barriers -> divergence-safe

    const int uid = user_idxs[b];
    const int iid = item_idxs[b];

    int nvu = 0, nvi = 0;
    if (lane < KN) {
        nvu = user_idx_tensor[uid * KN + lane];
        nvi = item_idx_tensor[iid * KN + lane];
    }

    f32x16 acc0 = {};   // C cols 0..31  (h1 cols = user half outputs 0..31)
    f32x16 acc1 = {};   // C cols 32..63

    #pragma unroll
    for (int side = 0; side < 2; ++side) {
        const float*  scr = side ? item_scr_tensor : user_scr_tensor;
        const ushort* Y   = (const ushort*)(side ? Yi : Yu);
        const int     nv  = side ? nvi : nvu;

        // ---- A frags: S row (l&31), k-octet 8g+j ; fp32 -> bf16 ----
        const int n_r = __shfl(nv, c);               // lanes>=20 -> nv junk=0, C rows>=20 unused
        const float* arow = scr + (size_t)n_r * KN;
        float4 a0 = *(const float4*)(arow + 8 * g);      // k = 8g..8g+3   (16B aligned: 80|32 bytes)
        float4 a1 = *(const float4*)(arow + 8 * g + 4);  // k = 8g+4..8g+7
        short8 A0;
        A0[0] = (short)f2bf(a0.x); A0[1] = (short)f2bf(a0.y);
        A0[2] = (short)f2bf(a0.z); A0[3] = (short)f2bf(a0.w);
        A0[4] = (short)f2bf(a1.x); A0[5] = (short)f2bf(a1.y);
        A0[6] = (short)f2bf(a1.z); A0[7] = (short)f2bf(a1.w);
        float4 a2 = *(const float4*)(arow + 16);         // k = 16..19 (ends exactly at row end)
        short8 A1 = {};                                  // k>=20 cols don't-care (B rows zero)
        A1[0] = (short)f2bf(a2.x); A1[1] = (short)f2bf(a2.y);
        A1[2] = (short)f2bf(a2.z); A1[3] = (short)f2bf(a2.w);

        // ---- B frags kstep0: rows k = 8g+j (all < 16 valid), col c / 32+c ----
        short8 B00, B01;
        #pragma unroll
        for (int j = 0; j < 8; ++j) {
            int nk = __shfl(nv, 8 * g + j);
            const ushort* yp = Y + (size_t)nk * DD;
            B00[j] = (short)yp[c];
            B01[j] = (short)yp[32 + c];
        }
        acc0 = __builtin_amdgcn_mfma_f32_32x32x16_bf16(A0, B00, acc0, 0, 0, 0);
        acc1 = __builtin_amdgcn_mfma_f32_32x32x16_bf16(A0, B01, acc1, 0, 0, 0);

        // ---- B frags kstep1: rows k = 16+8g+j; valid only g0 & j<4, else ZERO ----
        short8 B10 = {}, B11 = {};
        #pragma unroll
        for (int j = 0; j < 4; ++j) {
            int nk = __shfl(nv, 16 + 8 * g + j);
            if (g == 0) {                              // exec-masked loads; g1 keeps zeros
                const ushort* yp = Y + (size_t)nk * DD;
                B10[j] = (short)yp[c];
                B11[j] = (short)yp[32 + c];
            }
        }
        acc0 = __builtin_amdgcn_mfma_f32_32x32x16_bf16(A1, B10, acc0, 0, 0, 0);
        acc1 = __builtin_amdgcn_mfma_f32_32x32x16_bf16(A1, B11, acc1, 0, 0, 0);
    }

    // ---- bias + relu -> h1 rows<20 into wave-private LDS ----
    const float b1v0 = b1[c];
    const float b1v1 = b1[32 + c];
    #pragma unroll
    for (int r = 0; r < 12; ++r) {                      // r>=12 -> rows>=24, never valid
        const int row = (r & 3) + 8 * (r >> 2) + 4 * g;
        if (row < KN) {                                 // r<8 always; r 8..11 only g0
            buf[w][row * DD + c]      = fmaxf(acc0[r] + b1v0, 0.f);
            buf[w][row * DD + 32 + c] = fmaxf(acc1[r] + b1v1, 0.f);
        }
    }

    // ---- layer2 (half-wave c-split) + layer3 + sigmoid + mean (as R7) ----
    const int h = g, o = c;
    float wreg2[32];
    #pragma unroll
    for (int cc = 0; cc < 32; ++cc)
        wreg2[cc] = w2[(h * 32 + cc) * 32 + o];
    const float b2v = b2[o];
    const float w3v = w3[o];
    const float b3v = b3[0];

    float sum = 0.f;
    #pragma unroll
    for (int k = 0; k < KN; ++k) {
        const float4* hp = (const float4*)&buf[w][k * DD + h * 32];
        float a = 0.f;
        #pragma unroll
        for (int q = 0; q < 8; ++q) {
            float4 v = hp[q];
            a = fmaf(v.x, wreg2[4*q+0], a);
            a = fmaf(v.y, wreg2[4*q+1], a);
            a = fmaf(v.z, wreg2[4*q+2], a);
            a = fmaf(v.w, wreg2[4*q+3], a);
        }
        float h2 = a + __shfl_xor(a, 32) + b2v;   // combine the two c-halves
        h2 = fmaxf(h2, 0.f);
        float p = h2 * w3v;
        #pragma unroll
        for (int off = 16; off > 0; off >>= 1)
            p += __shfl_xor(p, off);              // reduce over 32 out-cols
        float logit = p + b3v;
        sum += 1.f / (1.f + __expf(-logit));
    }
    if (lane == 0) out[b] = sum * (1.f / KN);
}

extern "C" void kernel_launch(void* const* d_in, const int* in_sizes, int n_in,
                              void* d_out, int out_size, void* d_ws, size_t ws_size,
                              hipStream_t stream) {
    const int*   user_idxs       = (const int*)  d_in[0];
    const int*   item_idxs       = (const int*)  d_in[1];
    const int*   user_idx_tensor = (const int*)  d_in[2];
    const float* user_scr_tensor = (const float*)d_in[3];
    const int*   item_idx_tensor = (const int*)  d_in[4];
    const float* item_scr_tensor = (const float*)d_in[5];
    const float* user_emb        = (const float*)d_in[6];
    const float* item_emb        = (const float*)d_in[7];
    const float* w1 = (const float*)d_in[8];
    const float* b1 = (const float*)d_in[9];
    const float* w2 = (const float*)d_in[10];
    const float* b2 = (const float*)d_in[11];
    const float* w3 = (const float*)d_in[12];
    const float* b3 = (const float*)d_in[13];
    float* out = (float*)d_out;

    const int Bn = in_sizes[0];

    // workspace layout: Yu bf16 [100000][64] then Yi bf16 [50000][64]
    bf16* Yu = (bf16*)d_ws;
    bf16* Yi = Yu + (size_t)NUSERS * DD;

    precompute_Y<<<NBU + NBI, 256, 0, stream>>>(user_emb, item_emb, w1, Yu, Yi);

    const int grid = (Bn + WPB - 1) / WPB;
    cnn_main<<<grid, 256, 0, stream>>>(
        user_idxs, item_idxs, user_idx_tensor, user_scr_tensor,
        item_idx_tensor, item_scr_tensor, Yu, Yi,
        b1, w2, b2, w3, b3, out, Bn);
}

// Round 9
// 71.252 us; speedup vs baseline: 8.9482x; 1.2659x over previous
//
#include <hip/hip_runtime.h>
#include <hip/hip_bf16.h>
#include <math.h>

#define KN 20
#define DD 64
#define WPB 4
#define NUSERS 100000
#define NITEMS 50000
#define NBU 1024   // blocks assigned to user table
#define NBI 512    // blocks assigned to item table

typedef __hip_bfloat16 bf16;
typedef __attribute__((ext_vector_type(8))) short short8;   // 8 bf16 (4 VGPRs)
typedef __attribute__((ext_vector_type(16))) float f32x16;  // MFMA 32x32 acc

__device__ inline ushort f2bf(float f) {                    // fp32 -> bf16 RNE
    unsigned u = __builtin_bit_cast(unsigned, f);
    u += 0x7fffu + ((u >> 16) & 1u);
    return (ushort)(u >> 16);
}

// ================= precompute Y = emb_table @ W1part, + w2 -> bf16 frag table ==
__global__ __launch_bounds__(256, 4) void precompute_Y(
    const float* __restrict__ emb_u, const float* __restrict__ emb_i,
    const float* __restrict__ w1, const float* __restrict__ w2,
    bf16* __restrict__ Yu, bf16* __restrict__ Yi, ushort* __restrict__ w2b)
{
    __shared__ float stage[WPB][256];
    const int w    = threadIdx.x >> 6;
    const int lane = threadIdx.x & 63;

    // last block additionally emits w2 in MFMA-B fragment order:
    // w2b[((t*2+g)*32+o)*8+j] = bf16(w2[(16t+8g+j)*32+o]); tid = (t*2+g)*32+o
    if ((int)blockIdx.x == NBU + NBI - 1) {
        const int tid = threadIdx.x;
        const int t = tid >> 6, gg = (tid >> 5) & 1, o = tid & 31;
        #pragma unroll
        for (int j = 0; j < 8; ++j)
            w2b[(size_t)tid * 8 + j] = f2bf(w2[(16 * t + 8 * gg + j) * 32 + o]);
    }

    const bool isU = (int)blockIdx.x < NBU;
    const float* __restrict__ emb  = isU ? emb_u : emb_i;
    bf16* __restrict__       Y     = isU ? Yu : Yi;
    const float* __restrict__ wsrc = isU ? w1 : (w1 + 64 * DD);
    const int ngroups = (isU ? NUSERS : NITEMS) / 4;
    const int bidx    = isU ? (int)blockIdx.x : ((int)blockIdx.x - NBU);
    const int nwaves  = (isU ? NBU : NBI) * WPB;
    const int wid     = bidx * WPB + w;

    float wreg[64];
    #pragma unroll
    for (int c = 0; c < 64; ++c) wreg[c] = wsrc[c * DD + lane];

    for (int g = wid; g < ngroups; g += nwaves) {
        float4 v = *(const float4*)&emb[(size_t)g * 256 + lane * 4];
        *(float4*)&stage[w][lane * 4] = v;
        #pragma unroll
        for (int r = 0; r < 4; ++r) {
            float a0 = 0.f, a1 = 0.f, a2 = 0.f, a3 = 0.f;
            #pragma unroll
            for (int q = 0; q < 16; ++q) {
                float4 e4 = *(const float4*)&stage[w][r * 64 + q * 4];
                a0 = fmaf(e4.x, wreg[q * 4 + 0], a0);
                a1 = fmaf(e4.y, wreg[q * 4 + 1], a1);
                a2 = fmaf(e4.z, wreg[q * 4 + 2], a2);
                a3 = fmaf(e4.w, wreg[q * 4 + 3], a3);
            }
            Y[(size_t)(g * 4 + r) * DD + lane] = (bf16)((a0 + a1) + (a2 + a3));
        }
    }
}

// ================= main fused kernel ==========================================
// GEMM1 (h1 = Su@Yu_g + Si@Yi_g) on MFMA as R8 (verified layouts).
// NEW: h1 -> bf16 XOR-swizzled LDS; layer2 h2=h1@w2 as 4x mfma_32x32x16_bf16
// (A from LDS, B=w2b frag table); layer3 butterfly-reduce on C regs.
// Swizzle: 16B chunk index ^= (row&7) -- row-major [32][64]bf16 has 128B row
// stride = 32-way bank conflict otherwise (G4).
__global__ __launch_bounds__(256, 4) void cnn_main(
    const int* __restrict__ user_idxs, const int* __restrict__ item_idxs,
    const int* __restrict__ user_idx_tensor, const float* __restrict__ user_scr_tensor,
    const int* __restrict__ item_idx_tensor, const float* __restrict__ item_scr_tensor,
    const bf16* __restrict__ Yu, const bf16* __restrict__ Yi,
    const float* __restrict__ b1, const ushort* __restrict__ w2b,
    const float* __restrict__ b2,
    const float* __restrict__ w3, const float* __restrict__ b3,
    float* __restrict__ out, int Bn)
{
    __shared__ ushort h1b[WPB][32 * DD];   // bf16 h1, swizzled; 4KB/slot

    const int w    = threadIdx.x >> 6;
    const int lane = threadIdx.x & 63;
    const int g    = lane >> 5;            // half-wave group (k-octet select)
    const int c    = lane & 31;            // tile column / row index
    const int b = blockIdx.x * WPB + w;
    if (b >= Bn) return;                   // no barriers -> divergence-safe

    const int uid = user_idxs[b];
    const int iid = item_idxs[b];

    int nvu = 0, nvi = 0;
    if (lane < KN) {
        nvu = user_idx_tensor[uid * KN + lane];
        nvi = item_idx_tensor[iid * KN + lane];
    }

    f32x16 acc0 = {};   // h1 cols 0..31
    f32x16 acc1 = {};   // h1 cols 32..63

    #pragma unroll
    for (int side = 0; side < 2; ++side) {
        const float*  scr = side ? item_scr_tensor : user_scr_tensor;
        const ushort* Y   = (const ushort*)(side ? Yi : Yu);
        const int     nv  = side ? nvi : nvu;

        // ---- A frags: S row (l&31), k-octet 8g+j ; fp32 -> bf16 ----
        const int n_r = __shfl(nv, c);
        const float* arow = scr + (size_t)n_r * KN;
        float4 a0 = *(const float4*)(arow + 8 * g);
        float4 a1 = *(const float4*)(arow + 8 * g + 4);
        short8 A0;
        A0[0] = (short)f2bf(a0.x); A0[1] = (short)f2bf(a0.y);
        A0[2] = (short)f2bf(a0.z); A0[3] = (short)f2bf(a0.w);
        A0[4] = (short)f2bf(a1.x); A0[5] = (short)f2bf(a1.y);
        A0[6] = (short)f2bf(a1.z); A0[7] = (short)f2bf(a1.w);
        float4 a2 = *(const float4*)(arow + 16);
        short8 A1 = {};                                  // k>=20 don't-care (B rows zero)
        A1[0] = (short)f2bf(a2.x); A1[1] = (short)f2bf(a2.y);
        A1[2] = (short)f2bf(a2.z); A1[3] = (short)f2bf(a2.w);

        // ---- B frags kstep0: rows k = 8g+j, col c / 32+c ----
        short8 B00, B01;
        #pragma unroll
        for (int j = 0; j < 8; ++j) {
            int nk = __shfl(nv, 8 * g + j);
            const ushort* yp = Y + (size_t)nk * DD;
            B00[j] = (short)yp[c];
            B01[j] = (short)yp[32 + c];
        }
        acc0 = __builtin_amdgcn_mfma_f32_32x32x16_bf16(A0, B00, acc0, 0, 0, 0);
        acc1 = __builtin_amdgcn_mfma_f32_32x32x16_bf16(A0, B01, acc1, 0, 0, 0);

        // ---- B frags kstep1: rows k = 16+8g+j; valid only g0 & j<4 ----
        short8 B10 = {}, B11 = {};
        #pragma unroll
        for (int j = 0; j < 4; ++j) {
            int nk = __shfl(nv, 16 + 8 * g + j);
            if (g == 0) {
                const ushort* yp = Y + (size_t)nk * DD;
                B10[j] = (short)yp[c];
                B11[j] = (short)yp[32 + c];
            }
        }
        acc0 = __builtin_amdgcn_mfma_f32_32x32x16_bf16(A1, B10, acc0, 0, 0, 0);
        acc1 = __builtin_amdgcn_mfma_f32_32x32x16_bf16(A1, B11, acc1, 0, 0, 0);
    }

    // ---- bias + relu -> bf16 -> swizzled wave-private LDS (rows < 20) ----
    const float b1v0 = b1[c];
    const float b1v1 = b1[32 + c];
    #pragma unroll
    for (int r = 0; r < 12; ++r) {
        const int row = (r & 3) + 8 * (r >> 2) + 4 * g;
        if (row < KN) {
            const int ch0 = (c >> 3) ^ (row & 7);
            const int ch1 = (4 + (c >> 3)) ^ (row & 7);
            h1b[w][row * DD + ch0 * 8 + (c & 7)] = f2bf(fmaxf(acc0[r] + b1v0, 0.f));
            h1b[w][row * DD + ch1 * 8 + (c & 7)] = f2bf(fmaxf(acc1[r] + b1v1, 0.f));
        }
    }

    // ---- layer2 MFMA: h2(20x32) = h1(20x64) @ w2(64x32), 4 K-steps ----
    const int ar = (c < KN) ? c : 0;       // clamp A row (rows>=20 don't-care)
    f32x16 c2 = {};
    #pragma unroll
    for (int t = 0; t < 4; ++t) {
        const int chunk = (2 * t + g) ^ (ar & 7);
        short8 A = *(const short8*)&h1b[w][ar * DD + chunk * 8];
        short8 B = *(const short8*)&w2b[(size_t)(((t * 2 + g) * 32 + c)) * 8];
        c2 = __builtin_amdgcn_mfma_f32_32x32x16_bf16(A, B, c2, 0, 0, 0);
    }

    // ---- layer3: bias+relu, *w3, butterfly over 32 cols, sigmoid, mean ----
    const float b2v = b2[c];
    const float w3v = w3[c];
    const float b3v = b3[0];
    float sum = 0.f;
    #pragma unroll
    for (int r = 0; r < 12; ++r) {
        float h2v = fmaxf(c2[r] + b2v, 0.f);
        float p = h2v * w3v;
        #pragma unroll
        for (int off = 16; off > 0; off >>= 1)
            p += __shfl_xor(p, off);               // sum over 32 out-cols
        float logit = p + b3v;
        if (g == 0 || r < 8)                       // valid rows: g0 12, g1 8 (=20)
            sum += 1.f / (1.f + __expf(-logit));
    }
    sum += __shfl_xor(sum, 32);
    if (lane == 0) out[b] = sum * (1.f / KN);
}

extern "C" void kernel_launch(void* const* d_in, const int* in_sizes, int n_in,
                              void* d_out, int out_size, void* d_ws, size_t ws_size,
                              hipStream_t stream) {
    const int*   user_idxs       = (const int*)  d_in[0];
    const int*   item_idxs       = (const int*)  d_in[1];
    const int*   user_idx_tensor = (const int*)  d_in[2];
    const float* user_scr_tensor = (const float*)d_in[3];
    const int*   item_idx_tensor = (const int*)  d_in[4];
    const float* item_scr_tensor = (const float*)d_in[5];
    const float* user_emb        = (const float*)d_in[6];
    const float* item_emb        = (const float*)d_in[7];
    const float* w1 = (const float*)d_in[8];
    const float* b1 = (const float*)d_in[9];
    const float* w2 = (const float*)d_in[10];
    const float* b2 = (const float*)d_in[11];
    const float* w3 = (const float*)d_in[12];
    const float* b3 = (const float*)d_in[13];
    float* out = (float*)d_out;

    const int Bn = in_sizes[0];

    // workspace: Yu bf16 [100000][64] | Yi bf16 [50000][64] | w2b ushort[2048]
    bf16*   Yu  = (bf16*)d_ws;
    bf16*   Yi  = Yu + (size_t)NUSERS * DD;
    ushort* w2b = (ushort*)(Yi + (size_t)NITEMS * DD);

    precompute_Y<<<NBU + NBI, 256, 0, stream>>>(user_emb, item_emb, w1, w2,
                                                Yu, Yi, w2b);

    const int grid = (Bn + WPB - 1) / WPB;
    cnn_main<<<grid, 256, 0, stream>>>(
        user_idxs, item_idxs, user_idx_tensor, user_scr_tensor,
        item_idx_tensor, item_scr_tensor, Yu, Yi,
        b1, w2b, b2, w3, b3, out, Bn);
}

// Round 10
// 61.206 us; speedup vs baseline: 10.4169x; 1.1641x over previous
//
#include <hip/hip_runtime.h>
#include <hip/hip_bf16.h>
#include <math.h>

#define KN 20
#define DD 64
#define WPB 4
#define NUSERS 100000
#define NITEMS 50000
#define NBU 1024   // blocks assigned to user table
#define NBI 512    // blocks assigned to item table
#define NBS 128    // score-convert blocks (only when ws is big enough)
#define SROW 24    // padded bf16 score row stride (48B, 16B-aligned, zeros 20..23)

typedef __hip_bfloat16 bf16;
typedef __attribute__((ext_vector_type(8))) short short8;   // 8 bf16 (4 VGPRs)
typedef __attribute__((ext_vector_type(16))) float f32x16;  // MFMA 32x32 acc

__device__ inline ushort f2bf(float f) {                    // fp32 -> bf16 RNE
    unsigned u = __builtin_bit_cast(unsigned, f);
    u += 0x7fffu + ((u >> 16) & 1u);
    return (ushort)(u >> 16);
}

// ====== precompute: Y = emb @ W1part; w2 -> frag table; scores -> bf16 ========
__global__ __launch_bounds__(256, 4) void precompute_Y(
    const float* __restrict__ emb_u, const float* __restrict__ emb_i,
    const float* __restrict__ w1, const float* __restrict__ w2,
    const float* __restrict__ uscr, const float* __restrict__ iscr,
    bf16* __restrict__ Yu, bf16* __restrict__ Yi, ushort* __restrict__ w2b,
    ushort* __restrict__ sbu, ushort* __restrict__ sbi)
{
    __shared__ float stage[WPB][256];
    const int w    = threadIdx.x >> 6;
    const int lane = threadIdx.x & 63;

    // ---- score tables -> bf16 (blocks >= NBU+NBI, launched only if big ws) ----
    if ((int)blockIdx.x >= NBU + NBI) {
        int t = ((int)blockIdx.x - (NBU + NBI)) * 256 + threadIdx.x;
        for (int r = t; r < NUSERS + NITEMS; r += NBS * 256) {
            const float* src = (r < NUSERS) ? (uscr + (size_t)r * KN)
                                            : (iscr + (size_t)(r - NUSERS) * KN);
            ushort* dst = (r < NUSERS) ? (sbu + (size_t)r * SROW)
                                       : (sbi + (size_t)(r - NUSERS) * SROW);
            ushort tmp[SROW];
            #pragma unroll
            for (int j = 0; j < KN; ++j) tmp[j] = f2bf(src[j]);
            #pragma unroll
            for (int j = KN; j < SROW; ++j) tmp[j] = 0;
            #pragma unroll
            for (int q = 0; q < SROW / 8; ++q)
                *(short8*)(dst + q * 8) = *(const short8*)(tmp + q * 8);
        }
        return;
    }

    // ---- w2 -> MFMA-B fragment order (one block) ----
    if ((int)blockIdx.x == NBU + NBI - 1) {
        const int tid = threadIdx.x;
        const int t = tid >> 6, gg = (tid >> 5) & 1, o = tid & 31;
        #pragma unroll
        for (int j = 0; j < 8; ++j)
            w2b[(size_t)tid * 8 + j] = f2bf(w2[(16 * t + 8 * gg + j) * 32 + o]);
    }

    const bool isU = (int)blockIdx.x < NBU;
    const float* __restrict__ emb  = isU ? emb_u : emb_i;
    bf16* __restrict__       Y     = isU ? Yu : Yi;
    const float* __restrict__ wsrc = isU ? w1 : (w1 + 64 * DD);
    const int ngroups = (isU ? NUSERS : NITEMS) / 4;
    const int bidx    = isU ? (int)blockIdx.x : ((int)blockIdx.x - NBU);
    const int nwaves  = (isU ? NBU : NBI) * WPB;
    const int wid     = bidx * WPB + w;

    float wreg[64];
    #pragma unroll
    for (int c = 0; c < 64; ++c) wreg[c] = wsrc[c * DD + lane];

    for (int g = wid; g < ngroups; g += nwaves) {
        float4 v = *(const float4*)&emb[(size_t)g * 256 + lane * 4];
        *(float4*)&stage[w][lane * 4] = v;
        #pragma unroll
        for (int r = 0; r < 4; ++r) {
            float a0 = 0.f, a1 = 0.f, a2 = 0.f, a3 = 0.f;
            #pragma unroll
            for (int q = 0; q < 16; ++q) {
                float4 e4 = *(const float4*)&stage[w][r * 64 + q * 4];
                a0 = fmaf(e4.x, wreg[q * 4 + 0], a0);
                a1 = fmaf(e4.y, wreg[q * 4 + 1], a1);
                a2 = fmaf(e4.z, wreg[q * 4 + 2], a2);
                a3 = fmaf(e4.w, wreg[q * 4 + 3], a3);
            }
            Y[(size_t)(g * 4 + r) * DD + lane] = (bf16)((a0 + a1) + (a2 + a3));
        }
    }
}

// ================= main fused kernel ==========================================
// GEMM1 on MFMA (R8/R9 verified layouts). NEW: Y rows staged via wave-private
// LDS (3 coalesced short8 row-gathers + linear ds_write_b128 per side); B-frags
// are ds_read_u16 with offset immediates (was 48 scalar global gathers/thread).
// SBF: scores pre-converted to bf16 (padded rows) -> A-frags are 2 direct 16B
// loads (deletes 24 runtime f2bf/thread); identical RNE rounding.
// h1 (bf16, XOR-swizzled) unions into the user staging region -- wave-private,
// DS ops execute in order per wave, so no barriers anywhere.
template<bool SBF>
__global__ __launch_bounds__(256, 4) void cnn_main(
    const int* __restrict__ user_idxs, const int* __restrict__ item_idxs,
    const int* __restrict__ user_idx_tensor, const float* __restrict__ uscr_f,
    const ushort* __restrict__ uscr_b,
    const int* __restrict__ item_idx_tensor, const float* __restrict__ iscr_f,
    const ushort* __restrict__ iscr_b,
    const bf16* __restrict__ Yu, const bf16* __restrict__ Yi,
    const float* __restrict__ b1, const ushort* __restrict__ w2b,
    const float* __restrict__ b2,
    const float* __restrict__ w3, const float* __restrict__ b3,
    float* __restrict__ out, int Bn)
{
    __shared__ ushort buf[WPB][3072];  // [side][24][64] staging; h1 reuses [0..1280)

    const int w    = threadIdx.x >> 6;
    const int lane = threadIdx.x & 63;
    const int g    = lane >> 5;            // half-wave group (k-octet select)
    const int c    = lane & 31;            // tile column / row index
    const int b = blockIdx.x * WPB + w;
    if (b >= Bn) return;                   // no barriers -> divergence-safe

    const int uid = user_idxs[b];
    const int iid = item_idxs[b];

    int nvu = 0, nvi = 0;
    if (lane < KN) {
        nvu = user_idx_tensor[uid * KN + lane];
        nvi = item_idx_tensor[iid * KN + lane];
    }

    // ---- stage Y rows (both sides) into wave-private LDS, coalesced ----
    #pragma unroll
    for (int side = 0; side < 2; ++side) {
        const ushort* Y = (const ushort*)(side ? Yi : Yu);
        const int nv = side ? nvi : nvu;
        #pragma unroll
        for (int i = 0; i < 3; ++i) {                 // rows 8i..8i+7 (16..23 pad junk)
            int nr = __shfl(nv, 8 * i + (lane >> 3)); // lanes>=KN give nv=0: safe
            short8 v = *(const short8*)(Y + (size_t)nr * DD + (lane & 7) * 8);
            *(short8*)&buf[w][side * 1536 + i * 512 + lane * 8] = v;
        }
    }

    f32x16 acc0 = {};   // h1 cols 0..31
    f32x16 acc1 = {};   // h1 cols 32..63

    #pragma unroll
    for (int side = 0; side < 2; ++side) {
        const int nv = side ? nvi : nvu;
        const int n_r = __shfl(nv, c);

        // ---- A frags: score row (l&31), k-octet 8g+j ----
        short8 A0, A1;
        if (SBF) {
            const ushort* sr = (side ? iscr_b : uscr_b) + (size_t)n_r * SROW;
            A0 = *(const short8*)(sr + 8 * g);     // k 8g..8g+7
            A1 = *(const short8*)(sr + 16);        // k 16..23 (20..23 are zeros)
        } else {
            const float* arow = (side ? iscr_f : uscr_f) + (size_t)n_r * KN;
            float4 a0 = *(const float4*)(arow + 8 * g);
            float4 a1 = *(const float4*)(arow + 8 * g + 4);
            A0[0] = (short)f2bf(a0.x); A0[1] = (short)f2bf(a0.y);
            A0[2] = (short)f2bf(a0.z); A0[3] = (short)f2bf(a0.w);
            A0[4] = (short)f2bf(a1.x); A0[5] = (short)f2bf(a1.y);
            A0[6] = (short)f2bf(a1.z); A0[7] = (short)f2bf(a1.w);
            float4 a2 = *(const float4*)(arow + 16);
            A1 = short8{};
            A1[0] = (short)f2bf(a2.x); A1[1] = (short)f2bf(a2.y);
            A1[2] = (short)f2bf(a2.z); A1[3] = (short)f2bf(a2.w);
        }

        // ---- B frags from LDS (base reg + offset immediates) ----
        const int sb0 = side * 1536;
        short8 B00, B01;
        #pragma unroll
        for (int j = 0; j < 8; ++j) {
            B00[j] = (short)buf[w][sb0 + (8 * g + j) * DD + c];
            B01[j] = (short)buf[w][sb0 + (8 * g + j) * DD + 32 + c];
        }
        acc0 = __builtin_amdgcn_mfma_f32_32x32x16_bf16(A0, B00, acc0, 0, 0, 0);
        acc1 = __builtin_amdgcn_mfma_f32_32x32x16_bf16(A0, B01, acc1, 0, 0, 0);

        short8 B10 = {}, B11 = {};
        if (g == 0) {                                  // rows 16..19; g1 keeps zeros
            #pragma unroll
            for (int j = 0; j < 4; ++j) {
                B10[j] = (short)buf[w][sb0 + (16 + j) * DD + c];
                B11[j] = (short)buf[w][sb0 + (16 + j) * DD + 32 + c];
            }
        }
        acc0 = __builtin_amdgcn_mfma_f32_32x32x16_bf16(A1, B10, acc0, 0, 0, 0);
        acc1 = __builtin_amdgcn_mfma_f32_32x32x16_bf16(A1, B11, acc1, 0, 0, 0);
    }

    // ---- bias + relu -> bf16 -> swizzled LDS rows<20 (reuses [0..1280)) ----
    const float b1v0 = b1[c];
    const float b1v1 = b1[32 + c];
    #pragma unroll
    for (int r = 0; r < 12; ++r) {
        const int row = (r & 3) + 8 * (r >> 2) + 4 * g;
        if (row < KN) {
            const int ch0 = (c >> 3) ^ (row & 7);
            const int ch1 = (4 + (c >> 3)) ^ (row & 7);
            buf[w][row * DD + ch0 * 8 + (c & 7)] = f2bf(fmaxf(acc0[r] + b1v0, 0.f));
            buf[w][row * DD + ch1 * 8 + (c & 7)] = f2bf(fmaxf(acc1[r] + b1v1, 0.f));
        }
    }

    // ---- layer2 MFMA: h2(20x32) = h1(20x64) @ w2(64x32), 4 K-steps ----
    const int ar = (c < KN) ? c : 0;       // clamp A row (rows>=20 don't-care)
    f32x16 c2 = {};
    #pragma unroll
    for (int t = 0; t < 4; ++t) {
        const int chunk = (2 * t + g) ^ (ar & 7);
        short8 A = *(const short8*)&buf[w][ar * DD + chunk * 8];
        short8 B = *(const short8*)&w2b[(size_t)(((t * 2 + g) * 32 + c)) * 8];
        c2 = __builtin_amdgcn_mfma_f32_32x32x16_bf16(A, B, c2, 0, 0, 0);
    }

    // ---- layer3: bias+relu, *w3, butterfly over 32 cols, sigmoid, mean ----
    const float b2v = b2[c];
    const float w3v = w3[c];
    const float b3v = b3[0];
    float sum = 0.f;
    #pragma unroll
    for (int r = 0; r < 12; ++r) {
        float h2v = fmaxf(c2[r] + b2v, 0.f);
        float p = h2v * w3v;
        #pragma unroll
        for (int off = 16; off > 0; off >>= 1)
            p += __shfl_xor(p, off);               // sum over 32 out-cols
        float logit = p + b3v;
        if (g == 0 || r < 8)                       // valid rows: g0 12, g1 8 (=20)
            sum += 1.f / (1.f + __expf(-logit));
    }
    sum += __shfl_xor(sum, 32);
    if (lane == 0) out[b] = sum * (1.f / KN);
}

extern "C" void kernel_launch(void* const* d_in, const int* in_sizes, int n_in,
                              void* d_out, int out_size, void* d_ws, size_t ws_size,
                              hipStream_t stream) {
    const int*   user_idxs       = (const int*)  d_in[0];
    const int*   item_idxs       = (const int*)  d_in[1];
    const int*   user_idx_tensor = (const int*)  d_in[2];
    const float* user_scr_tensor = (const float*)d_in[3];
    const int*   item_idx_tensor = (const int*)  d_in[4];
    const float* item_scr_tensor = (const float*)d_in[5];
    const float* user_emb        = (const float*)d_in[6];
    const float* item_emb        = (const float*)d_in[7];
    const float* w1 = (const float*)d_in[8];
    const float* b1 = (const float*)d_in[9];
    const float* w2 = (const float*)d_in[10];
    const float* b2 = (const float*)d_in[11];
    const float* w3 = (const float*)d_in[12];
    const float* b3 = (const float*)d_in[13];
    float* out = (float*)d_out;

    const int Bn = in_sizes[0];

    // ws: Yu bf16[100000*64] | Yi bf16[50000*64] | w2b u16[2048] | sbu | sbi
    bf16*   Yu  = (bf16*)d_ws;
    bf16*   Yi  = Yu + (size_t)NUSERS * DD;
    ushort* w2b = (ushort*)(Yi + (size_t)NITEMS * DD);
    ushort* sbu = w2b + 2048;
    ushort* sbi = sbu + (size_t)NUSERS * SROW;

    const size_t need = (size_t)(NUSERS + NITEMS) * DD * 2 + 2048 * 2
                      + (size_t)(NUSERS + NITEMS) * SROW * 2;
    const bool big = ws_size >= need;

    precompute_Y<<<NBU + NBI + (big ? NBS : 0), 256, 0, stream>>>(
        user_emb, item_emb, w1, w2, user_scr_tensor, item_scr_tensor,
        Yu, Yi, w2b, sbu, sbi);

    const int grid = (Bn + WPB - 1) / WPB;
    if (big)
        cnn_main<true><<<grid, 256, 0, stream>>>(
            user_idxs, item_idxs, user_idx_tensor, user_scr_tensor, sbu,
            item_idx_tensor, item_scr_tensor, sbi, Yu, Yi,
            b1, w2b, b2, w3, b3, out, Bn);
    else
        cnn_main<false><<<grid, 256, 0, stream>>>(
            user_idxs, item_idxs, user_idx_tensor, user_scr_tensor, sbu,
            item_idx_tensor, item_scr_tensor, sbi, Yu, Yi,
            b1, w2b, b2, w3, b3, out, Bn);
}